// Round 8
// baseline (317.612 us; speedup 1.0000x reference)
//
#include <hip/hip_runtime.h>
#include <hip/hip_bf16.h>

#define NU 262144
#define GG 128
#define PG 134          // padded field side (128 + 2*3)
#define DD 128
#define NCELL 4096      // 16^3 cells of 8^3 voxels

typedef __attribute__((ext_vector_type(8))) short short8;   // 8 bf16 (4 VGPR) MFMA frag
typedef __attribute__((ext_vector_type(4))) short short4v;  // 4 bf16
typedef __attribute__((ext_vector_type(4))) float f32x4;

// fp32 -> bf16, round-to-nearest-even (prep kernels)
__device__ __forceinline__ unsigned short f2b(float f) {
  union { float f; unsigned u; } v; v.f = f;
  unsigned r = v.u + 0x7fffu + ((v.u >> 16) & 1u);
  return (unsigned short)(r >> 16);
}
__device__ __forceinline__ float b2f(unsigned short b) {
  union { unsigned u; float f; } v; v.u = ((unsigned)b) << 16; return v.f;
}
// packed fp32x2 -> bf16x2 (RNE), single HW instruction
__device__ __forceinline__ unsigned cvtpk(float lo, float hi) {
  unsigned r;
  asm("v_cvt_pk_bf16_f32 %0, %1, %2" : "=v"(r) : "v"(lo), "v"(hi));
  return r;
}

__device__ __forceinline__ float fast_tanh(float x) {
  float ax = fabsf(x);
  float e  = __expf(ax + ax);
  float t  = 1.0f - __fdividef(2.0f, e + 1.0f);
  return copysignf(t, x);
}

// Row table: 128 neighborhood offsets = 18 full z-rows of 7 + one 2-elem stub (+1 dead row).
struct alignas(16) RowdT { int v[20]; };
static constexpr RowdT mkrowd() {
  RowdT t{};
  for (int r = 0; r < 20; ++r) {
    int rr = (r < 18) ? r : 18;
    int di = (rr < 18) ? (-3 + rr / 7) : -1;
    int dj = (rr < 18) ? (-3 + rr % 7) : 1;
    t.v[r] = (di * PG + dj) * PG - 3;
  }
  return t;
}
__device__ constexpr RowdT ROWD = mkrowd();

__device__ __forceinline__ int cell_of(float px, float py, float pz) {
  int cx = min(max((int)px, 0), GG - 1) >> 3;
  int cy = min(max((int)py, 0), GG - 1) >> 3;
  int cz = min(max((int)pz, 0), GG - 1) >> 3;
  return (cx << 8) | (cy << 4) | cz;
}

// ---------------- prep 1: clamped pad + bf16 convert of the field ----------------
__global__ void prep_field(const float* __restrict__ f, unsigned short* __restrict__ fp) {
  int idx = blockIdx.x * 256 + threadIdx.x;
  if (idx >= PG * PG * PG) return;
  int z = idx % PG, t = idx / PG;
  int y = t % PG, x = t / PG;
  int xx = min(max(x - 3, 0), GG - 1);
  int yy = min(max(y - 3, 0), GG - 1);
  int zz = min(max(z - 3, 0), GG - 1);
  fp[idx] = f2b(f[(xx * GG + yy) * GG + zz]);
}

// ---------------- prep 2: W1/W2 -> frag-major bf16 (W1 gather half row-reordered) ----
__global__ void prep_w(const float* __restrict__ W1, const float* __restrict__ W2,
                       unsigned short* __restrict__ w1t, unsigned short* __restrict__ w2t) {
  int idx = blockIdx.x * 256 + threadIdx.x;
  if (idx < 4608) {                            // W1: 9 kt * 8 nt * 64 lanes
    int kt = idx >> 9, nt = (idx >> 6) & 7, ln = idx & 63;
    int n = nt * 16 + (ln & 15);
    short8 s;
    if (kt < 4) {
      int k0 = kt * 32 + (ln >> 4) * 8;
#pragma unroll
      for (int j = 0; j < 8; ++j) s[j] = (short)f2b(W1[(k0 + j) * DD + n]);
    } else {
      int r = (kt - 4) * 4 + (ln >> 4);        // 0..19
#pragma unroll
      for (int j = 0; j < 8; ++j) {
        bool valid = (r < 18 && j < 7) || (r == 18 && j < 2);
        int row = 128 + ((r < 18) ? (r * 7 + j) : (126 + j));
        s[j] = valid ? (short)f2b(W1[row * DD + n]) : (short)0;
      }
    }
    ((short8*)w1t)[idx] = s;
  } else if (idx < 6656) {                     // W2: 4 kt * 8 nt * 64 lanes
    int c = idx - 4608;
    int kt = c >> 9, nt = (c >> 6) & 7, ln = c & 63;
    int n = nt * 16 + (ln & 15), k0 = kt * 32 + (ln >> 4) * 8;
    short8 s;
#pragma unroll
    for (int j = 0; j < 8; ++j) s[j] = (short)f2b(W2[(k0 + j) * DD + n]);
    ((short8*)w2t)[c] = s;
  }
}

// ---------------- counting sort by cell ----------------
__global__ void zero_k(int* __restrict__ cursor) {
  int i = blockIdx.x * 256 + threadIdx.x;
  if (i < NCELL) cursor[i] = 0;
}
__global__ void hist_k(const float* __restrict__ pos, int* __restrict__ cursor) {
  int u = blockIdx.x * 256 + threadIdx.x;
  atomicAdd(&cursor[cell_of(pos[u * 3], pos[u * 3 + 1], pos[u * 3 + 2])], 1);
}
__global__ void scan_k(int* __restrict__ cursor) {   // 1 block, 256 threads, 4096 bins
  __shared__ int sums[256];
  int t = threadIdx.x;
  int local[16];
  int partial = 0;
#pragma unroll
  for (int j = 0; j < 16; ++j) { local[j] = cursor[t * 16 + j]; partial += local[j]; }
  sums[t] = partial;
  __syncthreads();
  for (int off = 1; off < 256; off <<= 1) {
    int v = (t >= off) ? sums[t - off] : 0;
    __syncthreads();
    sums[t] += v;
    __syncthreads();
  }
  int excl = sums[t] - partial;
#pragma unroll
  for (int j = 0; j < 16; ++j) { cursor[t * 16 + j] = excl; excl += local[j]; }
}
__global__ void scatter_k(const float* __restrict__ pos, int* __restrict__ cursor,
                          int* __restrict__ perm) {
  int u = blockIdx.x * 256 + threadIdx.x;
  int dst = atomicAdd(&cursor[cell_of(pos[u * 3], pos[u * 3 + 1], pos[u * 3 + 2])], 1);
  perm[dst] = u;
}

// ---------------- permute pos/offs and sig(->bf16) into sorted order ----------------
__global__ void permute_pv(const float* __restrict__ pos, const float* __restrict__ offs,
                           const int* __restrict__ perm,
                           float* __restrict__ posP, float* __restrict__ offsP) {
  int u = blockIdx.x * 256 + threadIdx.x;
  int o = perm[u];
#pragma unroll
  for (int j = 0; j < 3; ++j) {
    posP[u * 3 + j]  = pos[o * 3 + j];
    offsP[u * 3 + j] = offs[o * 3 + j];
  }
}
__global__ void permute_sig(const float* __restrict__ sig, const int* __restrict__ perm,
                            unsigned short* __restrict__ sigbP) {
  int i = blockIdx.x * 256 + threadIdx.x;     // NU*16 chunks of 8 elems
  int u = i >> 4, c = i & 15;
  int o = perm[u];
  const f32x4* p = (const f32x4*)(sig + o * DD + c * 8);
  f32x4 a = p[0], b = p[1];
  short8 v;
  v[0] = (short)f2b(a[0]); v[1] = (short)f2b(a[1]);
  v[2] = (short)f2b(a[2]); v[3] = (short)f2b(a[3]);
  v[4] = (short)f2b(b[0]); v[5] = (short)f2b(b[1]);
  v[6] = (short)f2b(b[2]); v[7] = (short)f2b(b[3]);
  *(short8*)(sigbP + u * DD + c * 8) = v;
}

// ---------------- plain sig->bf16 (fallback mode 1) ----------------
__global__ void prep_sig(const float* __restrict__ s, unsigned short* __restrict__ sb) {
  int i = (blockIdx.x * 256 + threadIdx.x) * 8;
  const f32x4* p = (const f32x4*)(s + i);
  f32x4 a = p[0], b = p[1];
  short8 o;
  o[0] = (short)f2b(a[0]); o[1] = (short)f2b(a[1]);
  o[2] = (short)f2b(a[2]); o[3] = (short)f2b(a[3]);
  o[4] = (short)f2b(b[0]); o[5] = (short)f2b(b[1]);
  o[6] = (short)f2b(b[2]); o[7] = (short)f2b(b[3]);
  *(short8*)(sb + i) = o;
}

// ---------------- main kernel: 4 waves/block, wave = 32 units x {ev0, ev1} ----------------
// 8KB/wave LDS (32KB/block -> 4+ blocks/CU). GEMM2 k-split: stage h-half, MFMA, restage.
template<int MODE>
__global__ __launch_bounds__(256, 2) void atu_main(
    const float* __restrict__ pos, const float* __restrict__ sig,
    const unsigned short* __restrict__ sigb,
    const float* __restrict__ offs, const int* __restrict__ perm,
    const float* __restrict__ b1, const float* __restrict__ b2,
    const unsigned short* __restrict__ fpad,
    const short8* __restrict__ w1f, const short8* __restrict__ w2f,
    float* __restrict__ out_stab, float* __restrict__ out_pos)
{
  __shared__ unsigned short hs[4][4096];     // 8KB per wave (64 cols x 64 feats), 32KB total
  const int tid  = threadIdx.x;
  const int wid  = tid >> 6, lane = tid & 63;
  const int lg   = lane >> 4, lm = lane & 15;
  const int ubase = blockIdx.x * 128 + wid * 32;   // 32 units per wave, x2 evs
  char* hsb = (char*)&hs[wid][0];
  const char* fpadb = (const char*)fpad;

  // ---- gather bases: ut&1 = unit group, ut>>1 = ev ----
  int abase[4];
#pragma unroll
  for (int ut = 0; ut < 4; ++ut) {
    int u = ubase + (ut & 1) * 16 + lm;
    float px = pos[u * 3 + 0], py = pos[u * 3 + 1], pz = pos[u * 3 + 2];
    if (ut >= 2) { px += offs[u * 3 + 0]; py += offs[u * 3 + 1]; pz += offs[u * 3 + 2]; }
    int pcx = min(max((int)px, 0), GG - 1);
    int pcy = min(max((int)py, 0), GG - 1);
    int pcz = min(max((int)pz, 0), GG - 1);
    abase[ut] = ((pcx + 3) * PG + (pcy + 3)) * PG + (pcz + 3);
  }

#define FETCH_SIG(KT, DST)                                                        \
  {                                                                               \
    int kk = (KT);                                                                \
    _Pragma("unroll")                                                             \
    for (int ug = 0; ug < 2; ++ug) {                                              \
      int u = ubase + ug * 16 + lm;                                               \
      if constexpr (MODE >= 1) {                                                  \
        DST[ug] = *(const short8*)(sigb + u * DD + kk * 32 + lg * 8);             \
      } else {                                                                    \
        const f32x4* sp = (const f32x4*)(sig + (u * DD + kk * 32 + lg * 8));      \
        f32x4 s0 = sp[0], s1 = sp[1];                                             \
        short8 fr;                                                                \
        fr[0] = (short)f2b(s0[0]); fr[1] = (short)f2b(s0[1]);                     \
        fr[2] = (short)f2b(s0[2]); fr[3] = (short)f2b(s0[3]);                     \
        fr[4] = (short)f2b(s1[0]); fr[5] = (short)f2b(s1[1]);                     \
        fr[6] = (short)f2b(s1[2]); fr[7] = (short)f2b(s1[3]);                     \
        DST[ug] = fr;                                                             \
      }                                                                           \
    }                                                                             \
    DST[2] = DST[0]; DST[3] = DST[1];                                             \
  }

#define FETCH_ROW(KT, DST)                                                        \
  {                                                                               \
    int rd = ROWD.v[((KT) - 4) * 4 + lg];                                         \
    _Pragma("unroll")                                                             \
    for (int ut = 0; ut < 4; ++ut)                                                \
      DST[ut] = *(const short8*)(fpadb + 2 * (abase[ut] + rd));                   \
  }

  // ---- GEMM1: hT[128 feat][64 unit-ev cols], 9 kts, pipelined ----
  f32x4 acc[8][4];
#pragma unroll
  for (int nt = 0; nt < 8; ++nt)
#pragma unroll
    for (int ut = 0; ut < 4; ++ut) acc[nt][ut] = f32x4{0.f, 0.f, 0.f, 0.f};

  {
    short8 curf[4], nxtf[4];
    FETCH_SIG(0, curf);
#pragma unroll 1
    for (int kt = 0; kt < 9; ++kt) {
      if (kt < 3)       FETCH_SIG(kt + 1, nxtf)
      else if (kt < 8)  FETCH_ROW(kt + 1, nxtf)
      short8 af8[8];
#pragma unroll
      for (int nt = 0; nt < 8; ++nt) af8[nt] = w1f[(kt * 8 + nt) * 64 + lane];
#pragma unroll
      for (int nt = 0; nt < 8; ++nt)
#pragma unroll
        for (int ut = 0; ut < 4; ++ut)
          acc[nt][ut] = __builtin_amdgcn_mfma_f32_16x16x32_bf16(af8[nt], curf[ut], acc[nt][ut], 0, 0, 0);
      if (kt < 8) {
#pragma unroll
        for (int ut = 0; ut < 4; ++ut) curf[ut] = nxtf[ut];
      }
    }
  }

  // ---- GEMM2 with k-split h staging (8KB reused per half) + fused norm ----
  float ssq[4] = {0.f, 0.f, 0.f, 0.f};
  {
    f32x4 acc2[8][4];
#pragma unroll
    for (int nt = 0; nt < 8; ++nt)
#pragma unroll
      for (int ut = 0; ut < 4; ++ut) acc2[nt][ut] = f32x4{0.f, 0.f, 0.f, 0.f};

#pragma unroll 1
    for (int kh = 0; kh < 2; ++kh) {
      // stage h feats kh*64 .. kh*64+63 (bias + tanh + cvt_pk + swizzled LDS write)
#pragma unroll
      for (int n2 = 0; n2 < 4; ++n2) {
        int nt = kh * 4 + n2;
        f32x4 b1v = *(const f32x4*)(b1 + nt * 16 + lg * 4);
#pragma unroll
        for (int ut = 0; ut < 4; ++ut) {
          int u = ut * 16 + lm;
          float h0 = fast_tanh(acc[nt][ut][0] + b1v[0]);
          float h1 = fast_tanh(acc[nt][ut][1] + b1v[1]);
          float h2 = fast_tanh(acc[nt][ut][2] + b1v[2]);
          float h3 = fast_tanh(acc[nt][ut][3] + b1v[3]);
          unsigned q0 = cvtpk(h0, h1);
          unsigned q1 = cvtpk(h2, h3);
          int byte = (u * 128 + n2 * 32 + lg * 8) ^ ((u & 7) << 4);
          *(unsigned long long*)(hsb + byte) =
              (unsigned long long)q0 | ((unsigned long long)q1 << 32);
        }
      }
      // MFMA over this k-half (2 kts)
#pragma unroll 1
      for (int k2 = 0; k2 < 2; ++k2) {
        int kt = kh * 2 + k2;
        short8 hfr[4];
#pragma unroll
        for (int ut = 0; ut < 4; ++ut) {
          int u = ut * 16 + lm;
          int byte = (u * 128 + k2 * 64 + lg * 16) ^ ((u & 7) << 4);
          hfr[ut] = *(const short8*)(hsb + byte);
        }
        short8 af8[8];
#pragma unroll
        for (int nt = 0; nt < 8; ++nt) af8[nt] = w2f[(kt * 8 + nt) * 64 + lane];
#pragma unroll
        for (int nt = 0; nt < 8; ++nt)
#pragma unroll
          for (int ut = 0; ut < 4; ++ut)
            acc2[nt][ut] = __builtin_amdgcn_mfma_f32_16x16x32_bf16(af8[nt], hfr[ut], acc2[nt][ut], 0, 0, 0);
      }
    }

    // ---- || resp - sig ||^2  (sig compare loaded once per unit group) ----
#pragma unroll
    for (int nt = 0; nt < 8; ++nt) {
      f32x4 b2v = *(const f32x4*)(b2 + nt * 16 + lg * 4);
      f32x4 svg[2];
#pragma unroll
      for (int ug = 0; ug < 2; ++ug) {
        int u = ubase + ug * 16 + lm;
        if constexpr (MODE >= 1) {
          short4v hv = *(const short4v*)(sigb + u * DD + nt * 16 + lg * 4);
          svg[ug][0] = b2f((unsigned short)hv[0]); svg[ug][1] = b2f((unsigned short)hv[1]);
          svg[ug][2] = b2f((unsigned short)hv[2]); svg[ug][3] = b2f((unsigned short)hv[3]);
        } else {
          svg[ug] = *(const f32x4*)(sig + (u * DD + nt * 16 + lg * 4));
        }
      }
#pragma unroll
      for (int ut = 0; ut < 4; ++ut) {
#pragma unroll
        for (int r = 0; r < 4; ++r) {
          float d = acc2[nt][ut][r] + b2v[r] - svg[ut & 1][r];
          ssq[ut] = fmaf(d, d, ssq[ut]);
        }
      }
    }
  }

#pragma unroll
  for (int ut = 0; ut < 4; ++ut) {
    ssq[ut] += __shfl_xor(ssq[ut], 16, 64);
    ssq[ut] += __shfl_xor(ssq[ut], 32, 64);
  }

  // ---- accept / outputs: lanes 0..31 own units ubase + (lane&31) ----
  if (lane < 32) {
    float s0 = (lane & 16) ? ssq[1] : ssq[0];   // ev0
    float s1 = (lane & 16) ? ssq[3] : ssq[2];   // ev1
    int ul = ubase + (lane & 31);
    float px = pos[ul * 3 + 0], py = pos[ul * 3 + 1], pz = pos[ul * 3 + 2];
    float ox = offs[ul * 3 + 0], oy = offs[ul * 3 + 1], oz = offs[ul * 3 + 2];
    bool ok = s1 <= s0;
    int pu = (MODE == 2) ? perm[ul] : ul;
    out_stab[pu] = sqrtf(ok ? s1 : s0);
    out_pos[pu * 3 + 0] = ok ? px + ox : px;
    out_pos[pu * 3 + 1] = ok ? py + oy : py;
    out_pos[pu * 3 + 2] = ok ? pz + oz : pz;
  }
}

extern "C" void kernel_launch(void* const* d_in, const int* in_sizes, int n_in,
                              void* d_out, int out_size, void* d_ws, size_t ws_size,
                              hipStream_t stream) {
  const float* field = (const float*)d_in[0];
  const float* pos   = (const float*)d_in[1];
  const float* sig   = (const float*)d_in[2];
  const float* offs  = (const float*)d_in[3];
  const float* W1    = (const float*)d_in[4];
  const float* b1    = (const float*)d_in[5];
  const float* W2    = (const float*)d_in[6];
  const float* b2    = (const float*)d_in[7];
  float* out_stab = (float*)d_out;
  float* out_pos  = out_stab + NU;

  char* ws = (char*)d_ws;
  unsigned short* fpad  = (unsigned short*)ws;                    // 4,812,208 B (+slack)
  unsigned short* w1t   = (unsigned short*)(ws + 4812800);        // 73,728 B (9 kt)
  unsigned short* w2t   = (unsigned short*)(ws + 4886528);        // 32,768 B
  unsigned short* sigbP = (unsigned short*)(ws + 4919296);        // 67,108,864 B
  float*          posP  = (float*)(ws + 72028160);                // 3,145,728 B
  float*          offsP = (float*)(ws + 75173888);                // 3,145,728 B
  int*            perm  = (int*)(ws + 78319616);                  // 1,048,576 B
  int*            cursor= (int*)(ws + 79368192);                  // 16,384 B
  const size_t need2 = 79384576ull;
  const size_t need1 = 72028160ull;

  prep_field<<<(PG * PG * PG + 255) / 256, 256, 0, stream>>>(field, fpad);
  prep_w<<<26, 256, 0, stream>>>(W1, W2, w1t, w2t);

  if (ws_size >= need2) {
    zero_k<<<NCELL / 256, 256, 0, stream>>>(cursor);
    hist_k<<<NU / 256, 256, 0, stream>>>(pos, cursor);
    scan_k<<<1, 256, 0, stream>>>(cursor);
    scatter_k<<<NU / 256, 256, 0, stream>>>(pos, cursor, perm);
    permute_pv<<<NU / 256, 256, 0, stream>>>(pos, offs, perm, posP, offsP);
    permute_sig<<<NU * 16 / 256, 256, 0, stream>>>(sig, perm, sigbP);
    atu_main<2><<<NU / 128, 256, 0, stream>>>(posP, sig, sigbP, offsP, perm, b1, b2, fpad,
                                              (const short8*)w1t, (const short8*)w2t,
                                              out_stab, out_pos);
  } else if (ws_size >= need1) {
    prep_sig<<<NU * DD / 8 / 256, 256, 0, stream>>>(sig, sigbP);
    atu_main<1><<<NU / 128, 256, 0, stream>>>(pos, sig, sigbP, offs, nullptr, b1, b2, fpad,
                                              (const short8*)w1t, (const short8*)w2t,
                                              out_stab, out_pos);
  } else {
    atu_main<0><<<NU / 128, 256, 0, stream>>>(pos, sig, nullptr, offs, nullptr, b1, b2, fpad,
                                              (const short8*)w1t, (const short8*)w2t,
                                              out_stab, out_pos);
  }
}

// Round 9
// 196.189 us; speedup vs baseline: 1.6189x; 1.6189x over previous
//
#include <hip/hip_runtime.h>
#include <hip/hip_bf16.h>

#define NU 262144
#define GG 128
#define PG 134          // padded field side (128 + 2*3)
#define DD 128
#define NCELL 4096      // 16^3 cells of 8^3 voxels

typedef __attribute__((ext_vector_type(8))) short short8;   // 8 bf16 MFMA frag
typedef __attribute__((ext_vector_type(4))) float f32x4;

union Frag { short8 s; unsigned u[4]; };

// fp32 -> bf16 RNE (host-prep kernels)
__device__ __forceinline__ unsigned short f2b(float f) {
  union { float f; unsigned u; } v; v.f = f;
  unsigned r = v.u + 0x7fffu + ((v.u >> 16) & 1u);
  return (unsigned short)(r >> 16);
}
// packed fp32x2 -> bf16x2 (RNE HW instr)
__device__ __forceinline__ unsigned cvtpk(float lo, float hi) {
  unsigned r;
  asm("v_cvt_pk_bf16_f32 %0, %1, %2" : "=v"(r) : "v"(lo), "v"(hi));
  return r;
}

__device__ __forceinline__ float fast_tanh(float x) {
  float ax = fabsf(x);
  float e  = __expf(ax + ax);
  float t  = 1.0f - __fdividef(2.0f, e + 1.0f);
  return copysignf(t, x);
}

// 128 neighborhood offsets = 18 z-rows of 7 + one 2-elem stub (+1 dead row)
struct alignas(16) RowdT { int v[20]; };
static constexpr RowdT mkrowd() {
  RowdT t{};
  for (int r = 0; r < 20; ++r) {
    int rr = (r < 18) ? r : 18;
    int di = (rr < 18) ? (-3 + rr / 7) : -1;
    int dj = (rr < 18) ? (-3 + rr % 7) : 1;
    t.v[r] = (di * PG + dj) * PG - 3;
  }
  return t;
}
__device__ constexpr RowdT ROWD = mkrowd();

__device__ __forceinline__ int cell_of(float px, float py, float pz) {
  int cx = min(max((int)px, 0), GG - 1) >> 3;
  int cy = min(max((int)py, 0), GG - 1) >> 3;
  int cz = min(max((int)pz, 0), GG - 1) >> 3;
  return (cx << 8) | (cy << 4) | cz;
}

// ---------------- prep 1: clamped pad + bf16 field ----------------
__global__ void prep_field(const float* __restrict__ f, unsigned short* __restrict__ fp) {
  int idx = blockIdx.x * 256 + threadIdx.x;
  if (idx >= PG * PG * PG) return;
  int z = idx % PG, t = idx / PG;
  int y = t % PG, x = t / PG;
  int xx = min(max(x - 3, 0), GG - 1);
  int yy = min(max(y - 3, 0), GG - 1);
  int zz = min(max(z - 3, 0), GG - 1);
  fp[idx] = f2b(f[(xx * GG + yy) * GG + zz]);
}

// ---------------- prep 2: unified weight wall: 13 kt-blocks x 8KB ----------------
// kt 0-3: W1 sig half; kt 4-8: W1 gather rows (reordered, zero-padded); kt 9-12: W2.
__global__ void prep_w(const float* __restrict__ W1, const float* __restrict__ W2,
                       unsigned short* __restrict__ wall) {
  int idx = blockIdx.x * 256 + threadIdx.x;
  if (idx >= 6656) return;
  int kt = idx >> 9, nt = (idx >> 6) & 7, ln = idx & 63;
  int n = nt * 16 + (ln & 15), lg = ln >> 4;
  short8 s;
  if (kt < 4) {
    int k0 = kt * 32 + lg * 8;
#pragma unroll
    for (int j = 0; j < 8; ++j) s[j] = (short)f2b(W1[(k0 + j) * DD + n]);
  } else if (kt < 9) {
    int r = (kt - 4) * 4 + lg;                 // 0..19
#pragma unroll
    for (int j = 0; j < 8; ++j) {
      bool valid = (r < 18 && j < 7) || (r == 18 && j < 2);
      int row = 128 + ((r < 18) ? (r * 7 + j) : (126 + j));
      s[j] = valid ? (short)f2b(W1[row * DD + n]) : (short)0;
    }
  } else {
    int k0 = (kt - 9) * 32 + lg * 8;
#pragma unroll
    for (int j = 0; j < 8; ++j) s[j] = (short)f2b(W2[(k0 + j) * DD + n]);
  }
  ((short8*)wall)[idx] = s;
}

// ---------------- counting sort by cell ----------------
__global__ void zero_k(int* __restrict__ cursor) {
  int i = blockIdx.x * 256 + threadIdx.x;
  if (i < NCELL) cursor[i] = 0;
}
__global__ void hist_k(const float* __restrict__ pos, int* __restrict__ cursor) {
  int u = blockIdx.x * 256 + threadIdx.x;
  atomicAdd(&cursor[cell_of(pos[u * 3], pos[u * 3 + 1], pos[u * 3 + 2])], 1);
}
__global__ void scan_k(int* __restrict__ cursor) {
  __shared__ int sums[256];
  int t = threadIdx.x;
  int local[16];
  int partial = 0;
#pragma unroll
  for (int j = 0; j < 16; ++j) { local[j] = cursor[t * 16 + j]; partial += local[j]; }
  sums[t] = partial;
  __syncthreads();
  for (int off = 1; off < 256; off <<= 1) {
    int v = (t >= off) ? sums[t - off] : 0;
    __syncthreads();
    sums[t] += v;
    __syncthreads();
  }
  int excl = sums[t] - partial;
#pragma unroll
  for (int j = 0; j < 16; ++j) { cursor[t * 16 + j] = excl; excl += local[j]; }
}
__global__ void scatter_k(const float* __restrict__ pos, int* __restrict__ cursor,
                          int* __restrict__ perm) {
  int u = blockIdx.x * 256 + threadIdx.x;
  int dst = atomicAdd(&cursor[cell_of(pos[u * 3], pos[u * 3 + 1], pos[u * 3 + 2])], 1);
  perm[dst] = u;
}
__global__ void permute_pv(const float* __restrict__ pos, const float* __restrict__ offs,
                           const int* __restrict__ perm,
                           float* __restrict__ posP, float* __restrict__ offsP) {
  int u = blockIdx.x * 256 + threadIdx.x;
  int o = perm[u];
#pragma unroll
  for (int j = 0; j < 3; ++j) {
    posP[u * 3 + j]  = pos[o * 3 + j];
    offsP[u * 3 + j] = offs[o * 3 + j];
  }
}

// ---------------- main: 8 waves/block, wave = 16 units x {ev0, ev1} ----------------
// Weights stream through a 16KB rotating LDS buffer shared by all 8 waves.
// h transposed in-register (cvt_pk + ds_bpermute), sig read as f32 gathered via perm.
template<bool SORT>
__global__ __launch_bounds__(512, 4) void atu_main(
    const float* __restrict__ pos, const float* __restrict__ sig,
    const float* __restrict__ offs, const int* __restrict__ perm,
    const float* __restrict__ b1, const float* __restrict__ b2,
    const unsigned short* __restrict__ fpad, const unsigned short* __restrict__ wall,
    float* __restrict__ out_stab, float* __restrict__ out_pos)
{
  __shared__ unsigned short ldsw[2][4096];   // 2 x 8KB weight buffers
  const int tid  = threadIdx.x;
  const int lane = tid & 63;
  const int lg   = lane >> 4, lm = lane & 15;
  const int wid  = tid >> 6;
  int bid = blockIdx.x;
  int swz = (bid & 7) * 256 + (bid >> 3);      // XCD-bijective (2048 % 8 == 0)
  const int ub = swz * 128 + wid * 16;         // 16 units per wave

  const int pv = SORT ? perm[ub + lm] : (ub + lm);   // original unit index

  // gather bases: ev0 / ev1
  int abase[2];
  {
    int u = ub + lm;
    float px = pos[u * 3 + 0], py = pos[u * 3 + 1], pz = pos[u * 3 + 2];
    float qx = px + offs[u * 3 + 0], qy = py + offs[u * 3 + 1], qz = pz + offs[u * 3 + 2];
    int ax = min(max((int)px, 0), GG - 1), ay = min(max((int)py, 0), GG - 1), az = min(max((int)pz, 0), GG - 1);
    int bx = min(max((int)qx, 0), GG - 1), by = min(max((int)qy, 0), GG - 1), bz = min(max((int)qz, 0), GG - 1);
    abase[0] = ((ax + 3) * PG + (ay + 3)) * PG + (az + 3);
    abase[1] = ((bx + 3) * PG + (by + 3)) * PG + (bz + 3);
  }

  const short8* wfr = (const short8*)wall;     // frag idx = kt*512 + tid
  short8 wreg;

  // ---- prologue: stage weight block 0 ----
  wreg = wfr[tid];
  *(short8*)((char*)&ldsw[0][0] + tid * 16) = wreg;
  __syncthreads();

  f32x4 acc[8][2];
#pragma unroll
  for (int nt = 0; nt < 8; ++nt) { acc[nt][0] = f32x4{0.f,0.f,0.f,0.f}; acc[nt][1] = f32x4{0.f,0.f,0.f,0.f}; }

  // ---- GEMM1 kts 0-3: signature half (B shared by both evs; MFMA ev0 only) ----
#pragma unroll 1
  for (int kt = 0; kt < 4; ++kt) {
    wreg = wfr[(kt + 1) * 512 + tid];                        // issue next weight block
    const f32x4* sp = (const f32x4*)(sig + (size_t)pv * DD + kt * 32 + lg * 8);
    f32x4 a = sp[0], b = sp[1];
    Frag B;
    B.u[0] = cvtpk(a[0], a[1]); B.u[1] = cvtpk(a[2], a[3]);
    B.u[2] = cvtpk(b[0], b[1]); B.u[3] = cvtpk(b[2], b[3]);
    const char* buf = (const char*)&ldsw[kt & 1][0];
#pragma unroll
    for (int nt = 0; nt < 8; ++nt) {
      short8 af = *(const short8*)(buf + (nt * 64 + lane) * 16);
      acc[nt][0] = __builtin_amdgcn_mfma_f32_16x16x32_bf16(af, B.s, acc[nt][0], 0, 0, 0);
    }
    *(short8*)((char*)&ldsw[(kt + 1) & 1][0] + tid * 16) = wreg;  // write late
    __syncthreads();
  }

  // copy sig contribution to ev1
#pragma unroll
  for (int nt = 0; nt < 8; ++nt) acc[nt][1] = acc[nt][0];

  // ---- GEMM1 kts 4-8: gathered field rows (one 8-voxel z-row per frag) ----
  const char* fpadb = (const char*)fpad;
#pragma unroll 1
  for (int kt = 4; kt < 9; ++kt) {
    wreg = wfr[(kt + 1) * 512 + tid];
    int rd = ROWD.v[(kt - 4) * 4 + lg];
    short8 B0 = *(const short8*)(fpadb + 2 * (size_t)(abase[0] + rd));
    short8 B1 = *(const short8*)(fpadb + 2 * (size_t)(abase[1] + rd));
    const char* buf = (const char*)&ldsw[kt & 1][0];
#pragma unroll
    for (int nt = 0; nt < 8; ++nt) {
      short8 af = *(const short8*)(buf + (nt * 64 + lane) * 16);
      acc[nt][0] = __builtin_amdgcn_mfma_f32_16x16x32_bf16(af, B0, acc[nt][0], 0, 0, 0);
      acc[nt][1] = __builtin_amdgcn_mfma_f32_16x16x32_bf16(af, B1, acc[nt][1], 0, 0, 0);
    }
    *(short8*)((char*)&ldsw[(kt + 1) & 1][0] + tid * 16) = wreg;
    __syncthreads();
  }

  // ---- bias + tanh + pack h into Q[ev][nt][i] (bf16x2 words, lane-local) ----
  unsigned Q[2][8][2];
#pragma unroll
  for (int nt = 0; nt < 8; ++nt) {
    f32x4 b1v = *(const f32x4*)(b1 + nt * 16 + lg * 4);
#pragma unroll
    for (int ut = 0; ut < 2; ++ut) {
      float h0 = fast_tanh(acc[nt][ut][0] + b1v[0]);
      float h1 = fast_tanh(acc[nt][ut][1] + b1v[1]);
      float h2 = fast_tanh(acc[nt][ut][2] + b1v[2]);
      float h3 = fast_tanh(acc[nt][ut][3] + b1v[3]);
      Q[ut][nt][0] = cvtpk(h0, h1);
      Q[ut][nt][1] = cvtpk(h2, h3);
    }
  }

  // ---- GEMM2: resp = h*W2 + b2 (acc2 C-init = b2) ----
  f32x4 acc2[8][2];
#pragma unroll
  for (int nt = 0; nt < 8; ++nt) {
    f32x4 b2v = *(const f32x4*)(b2 + nt * 16 + lg * 4);
    acc2[nt][0] = b2v; acc2[nt][1] = b2v;
  }

  const int ad0 = ((((2 * lg) & 3) * 16) + lm) * 4;       // bpermute byte addrs
  const int ad1 = ((((2 * lg + 1) & 3) * 16) + lm) * 4;
  const bool hi = (lg >= 2);

#pragma unroll
  for (int kb = 0; kb < 4; ++kb) {
    int kt = 9 + kb;
    if (kt < 12) wreg = wfr[(kt + 1) * 512 + tid];
    // build B-frags from Q via cross-lane transpose
    Frag W[2];
#pragma unroll
    for (int ut = 0; ut < 2; ++ut) {
      int a0 = (int)Q[ut][2 * kb][0],     a1 = (int)Q[ut][2 * kb][1];
      int b0 = (int)Q[ut][2 * kb + 1][0], b1 = (int)Q[ut][2 * kb + 1][1];
      int r00 = __builtin_amdgcn_ds_bpermute(ad0, a0);
      int r01 = __builtin_amdgcn_ds_bpermute(ad0, a1);
      int r10 = __builtin_amdgcn_ds_bpermute(ad1, a0);
      int r11 = __builtin_amdgcn_ds_bpermute(ad1, a1);
      int s00 = __builtin_amdgcn_ds_bpermute(ad0, b0);
      int s01 = __builtin_amdgcn_ds_bpermute(ad0, b1);
      int s10 = __builtin_amdgcn_ds_bpermute(ad1, b0);
      int s11 = __builtin_amdgcn_ds_bpermute(ad1, b1);
      W[ut].u[0] = (unsigned)(hi ? s00 : r00);
      W[ut].u[1] = (unsigned)(hi ? s01 : r01);
      W[ut].u[2] = (unsigned)(hi ? s10 : r10);
      W[ut].u[3] = (unsigned)(hi ? s11 : r11);
    }
    const char* buf = (const char*)&ldsw[kt & 1][0];
#pragma unroll
    for (int nt = 0; nt < 8; ++nt) {
      short8 af = *(const short8*)(buf + (nt * 64 + lane) * 16);
      acc2[nt][0] = __builtin_amdgcn_mfma_f32_16x16x32_bf16(af, W[0].s, acc2[nt][0], 0, 0, 0);
      acc2[nt][1] = __builtin_amdgcn_mfma_f32_16x16x32_bf16(af, W[1].s, acc2[nt][1], 0, 0, 0);
    }
    if (kt < 12) {
      *(short8*)((char*)&ldsw[(kt + 1) & 1][0] + tid * 16) = wreg;
      __syncthreads();
    }
  }

  // ---- || resp - sig ||^2 (sig f32 direct, b2 already in acc2) ----
  float ssq[2] = {0.f, 0.f};
#pragma unroll
  for (int nt = 0; nt < 8; ++nt) {
    f32x4 sv = *(const f32x4*)(sig + (size_t)pv * DD + nt * 16 + lg * 4);
#pragma unroll
    for (int ut = 0; ut < 2; ++ut) {
#pragma unroll
      for (int r = 0; r < 4; ++r) {
        float d = acc2[nt][ut][r] - sv[r];
        ssq[ut] = fmaf(d, d, ssq[ut]);
      }
    }
  }
  ssq[0] += __shfl_xor(ssq[0], 16, 64); ssq[0] += __shfl_xor(ssq[0], 32, 64);
  ssq[1] += __shfl_xor(ssq[1], 16, 64); ssq[1] += __shfl_xor(ssq[1], 32, 64);

  // ---- accept / outputs: lanes 0..15, scatter via pv ----
  if (lane < 16) {
    int ul = ub + lm;
    float px = pos[ul * 3 + 0], py = pos[ul * 3 + 1], pz = pos[ul * 3 + 2];
    float ox = offs[ul * 3 + 0], oy = offs[ul * 3 + 1], oz = offs[ul * 3 + 2];
    bool ok = ssq[1] <= ssq[0];
    out_stab[pv] = sqrtf(ok ? ssq[1] : ssq[0]);
    out_pos[pv * 3 + 0] = ok ? px + ox : px;
    out_pos[pv * 3 + 1] = ok ? py + oy : py;
    out_pos[pv * 3 + 2] = ok ? pz + oz : pz;
  }
}

extern "C" void kernel_launch(void* const* d_in, const int* in_sizes, int n_in,
                              void* d_out, int out_size, void* d_ws, size_t ws_size,
                              hipStream_t stream) {
  const float* field = (const float*)d_in[0];
  const float* pos   = (const float*)d_in[1];
  const float* sig   = (const float*)d_in[2];
  const float* offs  = (const float*)d_in[3];
  const float* W1    = (const float*)d_in[4];
  const float* b1    = (const float*)d_in[5];
  const float* W2    = (const float*)d_in[6];
  const float* b2    = (const float*)d_in[7];
  float* out_stab = (float*)d_out;
  float* out_pos  = out_stab + NU;

  char* ws = (char*)d_ws;
  unsigned short* fpad  = (unsigned short*)ws;                 // 4,812,208 B (+slack)
  unsigned short* wall  = (unsigned short*)(ws + 4812800);     // 106,496 B (13 x 8KB)
  float*          posP  = (float*)(ws + 4919296);              // 3,145,728 B
  float*          offsP = (float*)(ws + 8065024);              // 3,145,728 B
  int*            perm  = (int*)(ws + 11210752);               // 1,048,576 B
  int*            cursor= (int*)(ws + 12259328);               // 16,384 B
  const size_t need_sort  = 12275712ull;
  const size_t need_plain = 4919296ull;

  prep_field<<<(PG * PG * PG + 255) / 256, 256, 0, stream>>>(field, fpad);
  prep_w<<<26, 256, 0, stream>>>(W1, W2, wall);

  if (ws_size >= need_sort) {
    zero_k<<<NCELL / 256, 256, 0, stream>>>(cursor);
    hist_k<<<NU / 256, 256, 0, stream>>>(pos, cursor);
    scan_k<<<1, 256, 0, stream>>>(cursor);
    scatter_k<<<NU / 256, 256, 0, stream>>>(pos, cursor, perm);
    permute_pv<<<NU / 256, 256, 0, stream>>>(pos, offs, perm, posP, offsP);
    atu_main<true><<<NU / 128, 512, 0, stream>>>(posP, sig, offsP, perm, b1, b2,
                                                 fpad, wall, out_stab, out_pos);
  } else if (ws_size >= need_plain) {
    atu_main<false><<<NU / 128, 512, 0, stream>>>(pos, sig, offs, nullptr, b1, b2,
                                                  fpad, wall, out_stab, out_pos);
  }
}

// Round 10
// 191.291 us; speedup vs baseline: 1.6604x; 1.0256x over previous
//
#include <hip/hip_runtime.h>
#include <hip/hip_bf16.h>

#define NU 262144
#define GG 128
#define PG 134          // padded field side (128 + 2*3)
#define DD 128
#define NCELL 4096      // 16^3 cells of 8^3 voxels

typedef __attribute__((ext_vector_type(8))) short short8;   // 8 bf16 MFMA frag
typedef __attribute__((ext_vector_type(4))) float f32x4;

union Frag { short8 s; unsigned u[4]; };

// fp32 -> bf16 RNE (prep kernels)
__device__ __forceinline__ unsigned short f2b(float f) {
  union { float f; unsigned u; } v; v.f = f;
  unsigned r = v.u + 0x7fffu + ((v.u >> 16) & 1u);
  return (unsigned short)(r >> 16);
}
// packed fp32x2 -> bf16x2 (RNE HW instr)
__device__ __forceinline__ unsigned cvtpk(float lo, float hi) {
  unsigned r;
  asm("v_cvt_pk_bf16_f32 %0, %1, %2" : "=v"(r) : "v"(lo), "v"(hi));
  return r;
}

__device__ __forceinline__ float fast_tanh(float x) {
  float ax = fabsf(x);
  float e  = __expf(ax + ax);
  float t  = 1.0f - __fdividef(2.0f, e + 1.0f);
  return copysignf(t, x);
}

// 128 neighborhood offsets = 18 z-rows of 7 + one 2-elem stub (+1 dead row)
struct alignas(16) RowdT { int v[20]; };
static constexpr RowdT mkrowd() {
  RowdT t{};
  for (int r = 0; r < 20; ++r) {
    int rr = (r < 18) ? r : 18;
    int di = (rr < 18) ? (-3 + rr / 7) : -1;
    int dj = (rr < 18) ? (-3 + rr % 7) : 1;
    t.v[r] = (di * PG + dj) * PG - 3;
  }
  return t;
}
__device__ constexpr RowdT ROWD = mkrowd();

__device__ __forceinline__ int cell_of(float px, float py, float pz) {
  int cx = min(max((int)px, 0), GG - 1) >> 3;
  int cy = min(max((int)py, 0), GG - 1) >> 3;
  int cz = min(max((int)pz, 0), GG - 1) >> 3;
  return (cx << 8) | (cy << 4) | cz;
}

// ---------------- prep 1: clamped pad + bf16 field ----------------
__global__ void prep_field(const float* __restrict__ f, unsigned short* __restrict__ fp) {
  int idx = blockIdx.x * 256 + threadIdx.x;
  if (idx >= PG * PG * PG) return;
  int z = idx % PG, t = idx / PG;
  int y = t % PG, x = t / PG;
  int xx = min(max(x - 3, 0), GG - 1);
  int yy = min(max(y - 3, 0), GG - 1);
  int zz = min(max(z - 3, 0), GG - 1);
  fp[idx] = f2b(f[(xx * GG + yy) * GG + zz]);
}

// ---------------- prep 2: weight wall (13 x 8KB) + cursor zero (fused) ----------------
// kt 0-3: W1 sig half; kt 4-8: W1 gather rows (reordered, zero-padded); kt 9-12: W2.
__global__ void prep_w(const float* __restrict__ W1, const float* __restrict__ W2,
                       unsigned short* __restrict__ wall, int* __restrict__ cursor) {
  int idx = blockIdx.x * 256 + threadIdx.x;
  if (cursor && idx < NCELL) cursor[idx] = 0;
  if (idx >= 6656) return;
  int kt = idx >> 9, nt = (idx >> 6) & 7, ln = idx & 63;
  int n = nt * 16 + (ln & 15), lg = ln >> 4;
  short8 s;
  if (kt < 4) {
    int k0 = kt * 32 + lg * 8;
#pragma unroll
    for (int j = 0; j < 8; ++j) s[j] = (short)f2b(W1[(k0 + j) * DD + n]);
  } else if (kt < 9) {
    int r = (kt - 4) * 4 + lg;                 // 0..19
#pragma unroll
    for (int j = 0; j < 8; ++j) {
      bool valid = (r < 18 && j < 7) || (r == 18 && j < 2);
      int row = 128 + ((r < 18) ? (r * 7 + j) : (126 + j));
      s[j] = valid ? (short)f2b(W1[row * DD + n]) : (short)0;
    }
  } else {
    int k0 = (kt - 9) * 32 + lg * 8;
#pragma unroll
    for (int j = 0; j < 8; ++j) s[j] = (short)f2b(W2[(k0 + j) * DD + n]);
  }
  ((short8*)wall)[idx] = s;
}

// ---------------- counting sort by cell ----------------
__global__ void hist_k(const float* __restrict__ pos, int* __restrict__ cursor) {
  int u = blockIdx.x * 256 + threadIdx.x;
  atomicAdd(&cursor[cell_of(pos[u * 3], pos[u * 3 + 1], pos[u * 3 + 2])], 1);
}
__global__ void scan_k(int* __restrict__ cursor) {
  __shared__ int sums[256];
  int t = threadIdx.x;
  int local[16];
  int partial = 0;
#pragma unroll
  for (int j = 0; j < 16; ++j) { local[j] = cursor[t * 16 + j]; partial += local[j]; }
  sums[t] = partial;
  __syncthreads();
  for (int off = 1; off < 256; off <<= 1) {
    int v = (t >= off) ? sums[t - off] : 0;
    __syncthreads();
    sums[t] += v;
    __syncthreads();
  }
  int excl = sums[t] - partial;
#pragma unroll
  for (int j = 0; j < 16; ++j) { cursor[t * 16 + j] = excl; excl += local[j]; }
}
// scatter + permute fused: write perm AND permuted pos/offs in one pass
__global__ void scatter_k(const float* __restrict__ pos, const float* __restrict__ offs,
                          int* __restrict__ cursor, int* __restrict__ perm,
                          float* __restrict__ posP, float* __restrict__ offsP) {
  int u = blockIdx.x * 256 + threadIdx.x;
  float px = pos[u * 3 + 0], py = pos[u * 3 + 1], pz = pos[u * 3 + 2];
  int dst = atomicAdd(&cursor[cell_of(px, py, pz)], 1);
  perm[dst] = u;
  posP[dst * 3 + 0] = px; posP[dst * 3 + 1] = py; posP[dst * 3 + 2] = pz;
  offsP[dst * 3 + 0] = offs[u * 3 + 0];
  offsP[dst * 3 + 1] = offs[u * 3 + 1];
  offsP[dst * 3 + 2] = offs[u * 3 + 2];
}

// ---------------- main: 8 waves/block, wave = 16 units x {ev0, ev1} ----------------
// Weights: 2-kt phases through 2x16KB LDS buffers, register prefetch depth 2,
// 7 barriers total. setprio(1) around MFMA clusters.
template<bool SORT>
__global__ __launch_bounds__(512, 4) void atu_main(
    const float* __restrict__ pos, const float* __restrict__ sig,
    const float* __restrict__ offs, const int* __restrict__ perm,
    const float* __restrict__ b1, const float* __restrict__ b2,
    const unsigned short* __restrict__ fpad, const unsigned short* __restrict__ wall,
    float* __restrict__ out_stab, float* __restrict__ out_pos)
{
  __shared__ unsigned short ldsw[2][8192];   // 2 x 16KB weight buffers (pair of kt-blocks)
  const int tid  = threadIdx.x;
  const int lane = tid & 63;
  const int lg   = lane >> 4, lm = lane & 15;
  const int wid  = tid >> 6;
  int bid = blockIdx.x;
  int swz = (bid & 7) * 256 + (bid >> 3);      // XCD-bijective (2048 % 8 == 0)
  const int ub = swz * 128 + wid * 16;         // 16 units per wave

  const int pv = SORT ? perm[ub + lm] : (ub + lm);   // original unit index

  // gather bases: ev0 / ev1
  int abase[2];
  {
    int u = ub + lm;
    float px = pos[u * 3 + 0], py = pos[u * 3 + 1], pz = pos[u * 3 + 2];
    float qx = px + offs[u * 3 + 0], qy = py + offs[u * 3 + 1], qz = pz + offs[u * 3 + 2];
    int ax = min(max((int)px, 0), GG - 1), ay = min(max((int)py, 0), GG - 1), az = min(max((int)pz, 0), GG - 1);
    int bx = min(max((int)qx, 0), GG - 1), by = min(max((int)qy, 0), GG - 1), bz = min(max((int)qz, 0), GG - 1);
    abase[0] = ((ax + 3) * PG + (ay + 3)) * PG + (az + 3);
    abase[1] = ((bx + 3) * PG + (by + 3)) * PG + (bz + 3);
  }

  const short8* wfr = (const short8*)wall;     // frag idx = kt*512 + tid
  const char* fpadb = (const char*)fpad;

  f32x4 acc[8][2];
#pragma unroll
  for (int nt = 0; nt < 8; ++nt) { acc[nt][0] = f32x4{0.f,0.f,0.f,0.f}; acc[nt][1] = f32x4{0.f,0.f,0.f,0.f}; }
  f32x4 acc2[8][2];
  unsigned Q[2][8][2];

#define WRBUF(H, R0, R1)                                                        \
  *(short8*)((char*)&ldsw[H][0] + tid * 16) = (R0);                             \
  *(short8*)((char*)&ldsw[H][0] + 8192 + tid * 16) = (R1);

#define SIG_KT(KT, HALF)                                                        \
  {                                                                             \
    const f32x4* sp = (const f32x4*)(sig + (size_t)pv * DD + (KT) * 32 + lg * 8); \
    f32x4 a = sp[0], b = sp[1];                                                 \
    Frag B;                                                                     \
    B.u[0] = cvtpk(a[0], a[1]); B.u[1] = cvtpk(a[2], a[3]);                     \
    B.u[2] = cvtpk(b[0], b[1]); B.u[3] = cvtpk(b[2], b[3]);                     \
    const char* buf = (const char*)&ldsw[HALF][0] + (((KT) & 1) ? 8192 : 0);    \
    __builtin_amdgcn_s_setprio(1);                                              \
    _Pragma("unroll")                                                           \
    for (int nt = 0; nt < 8; ++nt) {                                            \
      short8 af = *(const short8*)(buf + (nt * 64 + lane) * 16);                \
      acc[nt][0] = __builtin_amdgcn_mfma_f32_16x16x32_bf16(af, B.s, acc[nt][0], 0, 0, 0); \
    }                                                                           \
    __builtin_amdgcn_s_setprio(0);                                              \
  }

#define ROW_KT(KT, HALF)                                                        \
  {                                                                             \
    int rd = ROWD.v[((KT) - 4) * 4 + lg];                                       \
    short8 B0 = *(const short8*)(fpadb + 2 * (size_t)(abase[0] + rd));          \
    short8 B1 = *(const short8*)(fpadb + 2 * (size_t)(abase[1] + rd));          \
    const char* buf = (const char*)&ldsw[HALF][0] + (((KT) & 1) ? 8192 : 0);    \
    __builtin_amdgcn_s_setprio(1);                                              \
    _Pragma("unroll")                                                           \
    for (int nt = 0; nt < 8; ++nt) {                                            \
      short8 af = *(const short8*)(buf + (nt * 64 + lane) * 16);                \
      acc[nt][0] = __builtin_amdgcn_mfma_f32_16x16x32_bf16(af, B0, acc[nt][0], 0, 0, 0); \
      acc[nt][1] = __builtin_amdgcn_mfma_f32_16x16x32_bf16(af, B1, acc[nt][1], 0, 0, 0); \
    }                                                                           \
    __builtin_amdgcn_s_setprio(0);                                              \
  }

#define G2_KT(KT, HALF)                                                         \
  {                                                                             \
    constexpr int kb = (KT) - 9;                                                \
    Frag W[2];                                                                  \
    _Pragma("unroll")                                                           \
    for (int ut = 0; ut < 2; ++ut) {                                            \
      int qa0 = (int)Q[ut][2 * kb][0],     qa1 = (int)Q[ut][2 * kb][1];         \
      int qb0 = (int)Q[ut][2 * kb + 1][0], qb1 = (int)Q[ut][2 * kb + 1][1];     \
      int r00 = __builtin_amdgcn_ds_bpermute(ad0, qa0);                         \
      int r01 = __builtin_amdgcn_ds_bpermute(ad0, qa1);                         \
      int r10 = __builtin_amdgcn_ds_bpermute(ad1, qa0);                         \
      int r11 = __builtin_amdgcn_ds_bpermute(ad1, qa1);                         \
      int s00 = __builtin_amdgcn_ds_bpermute(ad0, qb0);                         \
      int s01 = __builtin_amdgcn_ds_bpermute(ad0, qb1);                         \
      int s10 = __builtin_amdgcn_ds_bpermute(ad1, qb0);                         \
      int s11 = __builtin_amdgcn_ds_bpermute(ad1, qb1);                         \
      W[ut].u[0] = (unsigned)(hi ? s00 : r00);                                  \
      W[ut].u[1] = (unsigned)(hi ? s01 : r01);                                  \
      W[ut].u[2] = (unsigned)(hi ? s10 : r10);                                  \
      W[ut].u[3] = (unsigned)(hi ? s11 : r11);                                  \
    }                                                                           \
    const char* buf = (const char*)&ldsw[HALF][0] + (((KT) & 1) ? 8192 : 0);    \
    __builtin_amdgcn_s_setprio(1);                                              \
    _Pragma("unroll")                                                           \
    for (int nt = 0; nt < 8; ++nt) {                                            \
      short8 af = *(const short8*)(buf + (nt * 64 + lane) * 16);                \
      acc2[nt][0] = __builtin_amdgcn_mfma_f32_16x16x32_bf16(af, W[0].s, acc2[nt][0], 0, 0, 0); \
      acc2[nt][1] = __builtin_amdgcn_mfma_f32_16x16x32_bf16(af, W[1].s, acc2[nt][1], 0, 0, 0); \
    }                                                                           \
    __builtin_amdgcn_s_setprio(0);                                              \
  }

  const int ad0 = ((((2 * lg) & 3) * 16) + lm) * 4;       // bpermute byte addrs
  const int ad1 = ((((2 * lg + 1) & 3) * 16) + lm) * 4;
  const bool hi = (lg >= 2);

  // ---- prologue: load pairs 0,1; stage pair0 ----
  short8 c0 = wfr[tid],        c1 = wfr[512 + tid];
  short8 n0 = wfr[1024 + tid], n1 = wfr[1536 + tid];
  WRBUF(0, c0, c1)
  __syncthreads();

  // P0: kts 0,1 (sig) from buf0; issue pair2; write pair1
  c0 = wfr[2048 + tid]; c1 = wfr[2560 + tid];
  SIG_KT(0, 0) SIG_KT(1, 0)
  WRBUF(1, n0, n1)
  __syncthreads();

  // P1: kts 2,3 (sig) from buf1; issue pair3; write pair2
  n0 = wfr[3072 + tid]; n1 = wfr[3584 + tid];
  SIG_KT(2, 1) SIG_KT(3, 1)
  WRBUF(0, c0, c1)
  __syncthreads();

  // sig contribution is shared by both evs
#pragma unroll
  for (int nt = 0; nt < 8; ++nt) acc[nt][1] = acc[nt][0];

  // P2: kts 4,5 (rows) from buf0; issue pair4; write pair3
  c0 = wfr[4096 + tid]; c1 = wfr[4608 + tid];
  ROW_KT(4, 0) ROW_KT(5, 0)
  WRBUF(1, n0, n1)
  __syncthreads();

  // P3: kts 6,7 (rows) from buf1; issue pair5; write pair4
  n0 = wfr[5120 + tid]; n1 = wfr[5632 + tid];
  ROW_KT(6, 1) ROW_KT(7, 1)
  WRBUF(0, c0, c1)
  __syncthreads();

  // P4: kt8 (row) + tanh/pack + kt9 (GEMM2) from buf0; issue block12; write pair5
  c0 = wfr[6144 + tid];
  ROW_KT(8, 0)

  // bias + tanh + pack h (lane-local bf16x2 words)
#pragma unroll
  for (int nt = 0; nt < 8; ++nt) {
    f32x4 b1v = *(const f32x4*)(b1 + nt * 16 + lg * 4);
#pragma unroll
    for (int ut = 0; ut < 2; ++ut) {
      float h0 = fast_tanh(acc[nt][ut][0] + b1v[0]);
      float h1 = fast_tanh(acc[nt][ut][1] + b1v[1]);
      float h2 = fast_tanh(acc[nt][ut][2] + b1v[2]);
      float h3 = fast_tanh(acc[nt][ut][3] + b1v[3]);
      Q[ut][nt][0] = cvtpk(h0, h1);
      Q[ut][nt][1] = cvtpk(h2, h3);
    }
  }
  // init acc2 with b2 (C-init)
#pragma unroll
  for (int nt = 0; nt < 8; ++nt) {
    f32x4 b2v = *(const f32x4*)(b2 + nt * 16 + lg * 4);
    acc2[nt][0] = b2v; acc2[nt][1] = b2v;
  }

  G2_KT(9, 0)
  WRBUF(1, n0, n1)
  __syncthreads();

  // P5: kts 10,11 (GEMM2) from buf1; write block12 to buf0 sub0
  G2_KT(10, 1) G2_KT(11, 1)
  *(short8*)((char*)&ldsw[0][0] + tid * 16) = c0;
  __syncthreads();

  // P6: kt12 (GEMM2) from buf0
  G2_KT(12, 0)

  // ---- || resp - sig ||^2 (sig f32 direct, b2 already in acc2) ----
  float ssq[2] = {0.f, 0.f};
#pragma unroll
  for (int nt = 0; nt < 8; ++nt) {
    f32x4 sv = *(const f32x4*)(sig + (size_t)pv * DD + nt * 16 + lg * 4);
#pragma unroll
    for (int ut = 0; ut < 2; ++ut) {
#pragma unroll
      for (int r = 0; r < 4; ++r) {
        float d = acc2[nt][ut][r] - sv[r];
        ssq[ut] = fmaf(d, d, ssq[ut]);
      }
    }
  }
  ssq[0] += __shfl_xor(ssq[0], 16, 64); ssq[0] += __shfl_xor(ssq[0], 32, 64);
  ssq[1] += __shfl_xor(ssq[1], 16, 64); ssq[1] += __shfl_xor(ssq[1], 32, 64);

  // ---- accept / outputs: lanes 0..15, scatter via pv ----
  if (lane < 16) {
    int ul = ub + lm;
    float px = pos[ul * 3 + 0], py = pos[ul * 3 + 1], pz = pos[ul * 3 + 2];
    float ox = offs[ul * 3 + 0], oy = offs[ul * 3 + 1], oz = offs[ul * 3 + 2];
    bool ok = ssq[1] <= ssq[0];
    out_stab[pv] = sqrtf(ok ? ssq[1] : ssq[0]);
    out_pos[pv * 3 + 0] = ok ? px + ox : px;
    out_pos[pv * 3 + 1] = ok ? py + oy : py;
    out_pos[pv * 3 + 2] = ok ? pz + oz : pz;
  }
#undef WRBUF
#undef SIG_KT
#undef ROW_KT
#undef G2_KT
}

extern "C" void kernel_launch(void* const* d_in, const int* in_sizes, int n_in,
                              void* d_out, int out_size, void* d_ws, size_t ws_size,
                              hipStream_t stream) {
  const float* field = (const float*)d_in[0];
  const float* pos   = (const float*)d_in[1];
  const float* sig   = (const float*)d_in[2];
  const float* offs  = (const float*)d_in[3];
  const float* W1    = (const float*)d_in[4];
  const float* b1    = (const float*)d_in[5];
  const float* W2    = (const float*)d_in[6];
  const float* b2    = (const float*)d_in[7];
  float* out_stab = (float*)d_out;
  float* out_pos  = out_stab + NU;

  char* ws = (char*)d_ws;
  unsigned short* fpad  = (unsigned short*)ws;                 // 4,812,208 B (+slack)
  unsigned short* wall  = (unsigned short*)(ws + 4812800);     // 106,496 B (13 x 8KB)
  float*          posP  = (float*)(ws + 4919296);              // 3,145,728 B
  float*          offsP = (float*)(ws + 8065024);              // 3,145,728 B
  int*            perm  = (int*)(ws + 11210752);               // 1,048,576 B
  int*            cursor= (int*)(ws + 12259328);               // 16,384 B
  const size_t need_sort  = 12275712ull;
  const size_t need_plain = 4919296ull;

  prep_field<<<(PG * PG * PG + 255) / 256, 256, 0, stream>>>(field, fpad);

  if (ws_size >= need_sort) {
    prep_w<<<26, 256, 0, stream>>>(W1, W2, wall, cursor);
    hist_k<<<NU / 256, 256, 0, stream>>>(pos, cursor);
    scan_k<<<1, 256, 0, stream>>>(cursor);
    scatter_k<<<NU / 256, 256, 0, stream>>>(pos, offs, cursor, perm, posP, offsP);
    atu_main<true><<<NU / 128, 512, 0, stream>>>(posP, sig, offsP, perm, b1, b2,
                                                 fpad, wall, out_stab, out_pos);
  } else if (ws_size >= need_plain) {
    prep_w<<<26, 256, 0, stream>>>(W1, W2, wall, nullptr);
    atu_main<false><<<NU / 128, 512, 0, stream>>>(pos, sig, offs, nullptr, b1, b2,
                                                  fpad, wall, out_stab, out_pos);
  }
}